// Round 16
// baseline (380.515 us; speedup 1.0000x reference)
//
#include <hip/hip_runtime.h>
#include <hip/hip_bf16.h>

#define B_   2
#define L_   2048
#define DIM_ 512
#define NH_  8
#define HD_  64
#define R_   8
#define EH_  16
#define T_   2

typedef unsigned int uint32;
typedef unsigned short ushort_t;

__device__ __forceinline__ float gelu_f(float x){
  return 0.5f * x * (1.0f + erff(x * 0.70710678118654752f));
}
__device__ __forceinline__ float softplus_f(float x){
  return (x > 20.f) ? x : log1pf(expf(x));
}
__device__ __forceinline__ constexpr int off_of(int o){ return (o < 4) ? o - 4 : o - 3; }
__device__ __forceinline__ ushort_t fbf(float f){
  uint32 u = __float_as_uint(f);
  return (ushort_t)((u + 0x7FFFu + ((u >> 16) & 1u)) >> 16);
}
__device__ __forceinline__ float blo(uint32 w){ return __uint_as_float(w << 16); }
__device__ __forceinline__ float bhi(uint32 w){ return __uint_as_float(w & 0xFFFF0000u); }

// ---------------------------------------------------------------------------
// k_misc: W2[h][n=k*8+r][d] (k<16: l2w, k==16: bias, k==17: zero pad),
//         eta, rope tables, init edge slot tables to -1.
// ---------------------------------------------------------------------------
__global__ __launch_bounds__(256) void k_misc(
    const float* __restrict__ l2w, const float* __restrict__ l2b,
    const float* __restrict__ step,
    float* __restrict__ W2, float* __restrict__ eta,
    float* __restrict__ ropeC, float* __restrict__ ropeS,
    int* __restrict__ esrc, int* __restrict__ edst)
{
  int idx = blockIdx.x * 256 + threadIdx.x;
  if (idx < NH_*144*64){
    int d = idx & 63;
    int n = (idx >> 6) % 144;
    int h = idx / (144*64);
    int k = n >> 3, r = n & 7;
    int col = h*512 + r*64 + d;
    float v = 0.f;
    if (k < 16) v = l2w[k*4096 + col];
    else if (k == 16) v = l2b[col];
    W2[idx] = v;
    return;
  }
  idx -= NH_*144*64;
  if (idx < T_*L_){ eta[idx] = softplus_f(step[idx]); return; }
  idx -= T_*L_;
  if (idx < 9*32){
    int d = idx & 31, rel = (idx >> 5) - 4;
    float invf = expf(-((float)d / 32.f) * 9.210340371976184f);  // ln(10000)
    float ang = (float)rel * invf;
    ropeC[idx] = cosf(ang); ropeS[idx] = sinf(ang);
    return;
  }
  idx -= 9*32;
  if (idx < 2*8*L_){
    if (idx < 8*L_) esrc[idx] = -1; else edst[idx - 8*L_] = -1;
    return;
  }
}

// ---------------------------------------------------------------------------
// k_cvtw: pair-packed bf16 W for k_S:
//   W2p[h][n][dp] = bf16(W[n][dp]) | bf16(W[n][dp+32])<<16,  dp in [0,32)
// ---------------------------------------------------------------------------
__global__ __launch_bounds__(256) void k_cvtw(
    const float* __restrict__ W2, uint32* __restrict__ W2p)
{
  int idx = blockIdx.x * 256 + threadIdx.x;
  if (idx >= NH_*144*32) return;
  int dp = idx & 31;
  int n  = (idx >> 5) % 144;
  int h  = idx / (144*32);
  const float* row = W2 + ((size_t)h*144 + n)*64;
  uint32 lo = fbf(row[dp]);
  uint32 hi = fbf(row[dp+32]);
  W2p[idx] = lo | (hi << 16);
}

// ---------------------------------------------------------------------------
// k_gram: Gram[h][r][a][b] = sum_d W2[h][a*8+r][d] * W2[h][b*8+r][d]
// ---------------------------------------------------------------------------
__global__ __launch_bounds__(256) void k_gram(
    const float* __restrict__ W2, float* __restrict__ Gram)
{
  int idx = blockIdx.x * 256 + threadIdx.x;
  if (idx >= 8*8*17*17) return;
  int bq = idx % 17;
  int a  = (idx / 17) % 17;
  int r  = (idx / 289) & 7;
  int h  = idx / (289*8);
  const float* wa = W2 + ((size_t)(h*144 + a*8 + r))*64;
  const float* wb = W2 + ((size_t)(h*144 + bq*8 + r))*64;
  float s = 0.f;
  #pragma unroll 8
  for (int d = 0; d < 64; d++) s = fmaf(wa[d], wb[d], s);
  Gram[idx] = s;
}

// ---------------------------------------------------------------------------
// k_fill: scatter edge ids into per-node slot tables.
// ---------------------------------------------------------------------------
__global__ __launch_bounds__(256) void k_fill(
    const int* __restrict__ ei, const int* __restrict__ ej, int E,
    int* __restrict__ esrc, int* __restrict__ edst)
{
  int e = blockIdx.x * 256 + threadIdx.x;
  if (e >= E) return;
  int i = ei[e], j = ej[e];
  int o = j - i;                      // in [-4,4] \ {0}
  int slot = (o < 0) ? (o + 4) : (o + 3);
  esrc[slot*L_ + i] = e;
  edst[slot*L_ + j] = e;
}

// ---------------------------------------------------------------------------
// k_te: u[(b*512 + n)*2048 + l] = x[b,l,:] @ te_w[:,n] + te_b[n]   (d-major u)
// ---------------------------------------------------------------------------
__global__ __launch_bounds__(256) void k_te(
    const float* __restrict__ x, const float* __restrict__ w,
    const float* __restrict__ bias, float* __restrict__ u)
{
  __shared__ float As[16][64];
  __shared__ float Bs[16][64];
  const int m0 = blockIdx.x * 64;
  const int n0 = blockIdx.y * 64;
  const int tid = threadIdx.x;
  const int ty = tid >> 4, tx = tid & 15;
  float acc[4][4] = {};
  for (int k0 = 0; k0 < 512; k0 += 16){
    {
      int m = tid >> 2, seg = tid & 3;
      float4 v = *(const float4*)(x + (size_t)(m0 + m)*512 + k0 + seg*4);
      As[seg*4+0][m] = v.x; As[seg*4+1][m] = v.y;
      As[seg*4+2][m] = v.z; As[seg*4+3][m] = v.w;
    }
    {
      int k = tid >> 4, c = (tid & 15)*4;
      float4 v = *(const float4*)(w + (size_t)(k0 + k)*512 + n0 + c);
      *(float4*)&Bs[k][c] = v;
    }
    __syncthreads();
    #pragma unroll
    for (int k = 0; k < 16; k++){
      float4 a = *(const float4*)(&As[k][ty*4]);
      float4 b = *(const float4*)(&Bs[k][tx*4]);
      float av[4] = {a.x, a.y, a.z, a.w};
      float bv[4] = {b.x, b.y, b.z, b.w};
      #pragma unroll
      for (int ii = 0; ii < 4; ii++)
        #pragma unroll
        for (int jj = 0; jj < 4; jj++)
          acc[ii][jj] = fmaf(av[ii], bv[jj], acc[ii][jj]);
    }
    __syncthreads();
  }
  const int bb = m0 >> 11;
  const int lb = (m0 & 2047) + ty*4;
  #pragma unroll
  for (int jj = 0; jj < 4; jj++){
    int n = n0 + tx*4 + jj;
    float bv = bias[n];
    float4 o;
    o.x = acc[0][jj] + bv; o.y = acc[1][jj] + bv;
    o.z = acc[2][jj] + bv; o.w = acc[3][jj] + bv;
    *(float4*)&u[((size_t)(bb*512 + n))*2048 + lb] = o;
  }
}

// ---------------------------------------------------------------------------
// k_pq: node projections for both edge MLPs.
// ---------------------------------------------------------------------------
__global__ __launch_bounds__(256) void k_pq(
    const float* __restrict__ x, const float* __restrict__ a1w,
    const float* __restrict__ l1w, float* __restrict__ PQ)
{
  __shared__ float As[16][64];
  __shared__ float Bs[16][64];
  const int m0 = blockIdx.x * 64;
  const int tid = threadIdx.x;
  const int ty = tid >> 4, tx = tid & 15;
  const int c = (tid & 15) * 4;
  const int group = c >> 4;                 // 0..3
  const float* src = (group & 2) ? l1w : a1w;
  const int krow_off = (group & 1) ? 512 : 0;
  const int cc = c & 15;
  float acc[4][4] = {};
  for (int k0 = 0; k0 < 512; k0 += 16){
    {
      int m = tid >> 2, seg = tid & 3;
      float4 v = *(const float4*)(x + (size_t)(m0 + m)*512 + k0 + seg*4);
      As[seg*4+0][m] = v.x; As[seg*4+1][m] = v.y;
      As[seg*4+2][m] = v.z; As[seg*4+3][m] = v.w;
    }
    {
      int k = tid >> 4;
      float4 v = *(const float4*)(src + (size_t)(krow_off + k0 + k)*16 + cc);
      *(float4*)&Bs[k][c] = v;
    }
    __syncthreads();
    #pragma unroll
    for (int k = 0; k < 16; k++){
      float4 a = *(const float4*)(&As[k][ty*4]);
      float4 b = *(const float4*)(&Bs[k][tx*4]);
      float av[4] = {a.x, a.y, a.z, a.w};
      float bv[4] = {b.x, b.y, b.z, b.w};
      #pragma unroll
      for (int ii = 0; ii < 4; ii++)
        #pragma unroll
        for (int jj = 0; jj < 4; jj++)
          acc[ii][jj] = fmaf(av[ii], bv[jj], acc[ii][jj]);
    }
    __syncthreads();
  }
  #pragma unroll
  for (int ii = 0; ii < 4; ii++){
    int m = m0 + ty*4 + ii;
    float4 o;
    o.x = acc[ii][0]; o.y = acc[ii][1]; o.z = acc[ii][2]; o.w = acc[ii][3];
    *(float4*)&PQ[(size_t)m*64 + tx*4] = o;
  }
}

// ---------------------------------------------------------------------------
// k_feat2: alphas + h2e (e-major) + h2t (k-major, for k_S global-m reads).
// ---------------------------------------------------------------------------
__global__ __launch_bounds__(256) void k_feat2(
    const float* __restrict__ PQ, const int* __restrict__ ei, const int* __restrict__ ej,
    const float* __restrict__ a1b, const float* __restrict__ a2w,
    const float* __restrict__ a2b, const float* __restrict__ l1b,
    int E, float* __restrict__ alphas, float* __restrict__ h2e,
    float* __restrict__ h2t)
{
  int e = blockIdx.x * 256 + threadIdx.x;
  int b = blockIdx.y;
  if (e >= E) return;
  int i = ei[e], j = ej[e];
  const float* Pi = PQ + ((size_t)b*L_ + i)*64;
  const float* Pj = PQ + ((size_t)b*L_ + j)*64;
  float ha[16], hl[16];
  #pragma unroll
  for (int q = 0; q < 4; q++){
    float4 p1 = *(const float4*)(Pi + q*4);
    float4 q1 = *(const float4*)(Pj + 16 + q*4);
    float4 p2 = *(const float4*)(Pi + 32 + q*4);
    float4 q2 = *(const float4*)(Pj + 48 + q*4);
    ha[q*4+0] = p1.x + q1.x; ha[q*4+1] = p1.y + q1.y;
    ha[q*4+2] = p1.z + q1.z; ha[q*4+3] = p1.w + q1.w;
    hl[q*4+0] = p2.x + q2.x; hl[q*4+1] = p2.y + q2.y;
    hl[q*4+2] = p2.z + q2.z; hl[q*4+3] = p2.w + q2.w;
  }
  float av = a2b[0];
  #pragma unroll
  for (int n = 0; n < 16; n++){
    float g = gelu_f(ha[n] + a1b[n]);
    av += g * a2w[n];
  }
  alphas[(size_t)b*E + e] = softplus_f(av);
  float* he = h2e + ((size_t)b*E + e)*16;
  #pragma unroll
  for (int n = 0; n < 16; n++){
    float g = gelu_f(hl[n] + l1b[n]);
    he[n] = g;
    h2t[((size_t)b*16 + n)*E + e] = g;
  }
}

// ---------------------------------------------------------------------------
// k_norm (once, u-independent): ivsq[bh][e][r] = 1/max(m17^T Gram_r m17, 1e-24)
// ---------------------------------------------------------------------------
__global__ __launch_bounds__(256) void k_norm(
    const float* __restrict__ Gram, const float* __restrict__ h2e,
    int E, float* __restrict__ ivsq)
{
  __shared__ float Gl[8*289];
  __shared__ float Hl[256*17];
  const int tid = threadIdx.x;
  const int bh = blockIdx.y;
  const int b = bh >> 3, h = bh & 7;
  const int eb = blockIdx.x*256;
  for (int it = tid; it < 2312; it += 256) Gl[it] = Gram[(size_t)h*2312 + it];
  {
    int ge = eb + tid;
    const float* hp = h2e + ((size_t)b*E + (ge < E ? ge : 0))*16;
    #pragma unroll
    for (int q = 0; q < 4; q++){
      float4 v = *(const float4*)(hp + q*4);
      Hl[tid*17+q*4+0]=v.x; Hl[tid*17+q*4+1]=v.y;
      Hl[tid*17+q*4+2]=v.z; Hl[tid*17+q*4+3]=v.w;
    }
    Hl[tid*17+16] = 1.f;
  }
  __syncthreads();
  int ge = eb + tid;
  if (ge >= E) return;
  float m17[17];
  #pragma unroll
  for (int k = 0; k < 17; k++) m17[k] = Hl[tid*17+k];
  float* ig = ivsq + ((size_t)bh*E + ge)*8;
  #pragma unroll
  for (int r = 0; r < 8; r++){
    float ss = 0.f;
    for (int a = 0; a < 17; a++){
      float ma = Hl[tid*17 + a];           // runtime idx -> LDS (no scratch)
      const float* Gr = Gl + r*289 + a*17;
      float inner = 0.f;
      #pragma unroll
      for (int bq = 0; bq < 17; bq++)
        inner = fmaf(m17[bq], Gr[bq], inner);
      ss = fmaf(ma, inner, ss);
    }
    ig[r] = 1.f / fmaxf(ss, 1e-24f);
  }
}

// ---------------------------------------------------------------------------
// k_S v7: 128 edges/block (2048 blocks = 2x grid), lane = 4 edges x 4
// rope-pairs (8-way d split, og = tid&7). W pair-packed bf16: one uint4 read
// = 4 (dp, dp+32) pairs shared across 4 edges; 136 reads/thread. Reduce via
// shfl_xor(1,2,4). Registers ~2/3 of v4 -> 5 waves/SIMD.
// LDS: Wl 17.4 KB + rope 2.3 KB = 19.7 KB.
// ---------------------------------------------------------------------------
__global__ __launch_bounds__(256) void k_S(
    const float* __restrict__ u, const uint32* __restrict__ W2p,
    const float* __restrict__ h2t,
    const float* __restrict__ ropeC, const float* __restrict__ ropeS,
    const int* __restrict__ ei, const int* __restrict__ ej,
    int E, const float* __restrict__ ivsq, float* __restrict__ coefg)
{
  __shared__ uint32 Wl[136*32];        // rows of 32 packed dwords (128 B)
  __shared__ float rCT[288], rST[288]; // [p][rix] stride 9
  const int tid = threadIdx.x;
  const int bh = blockIdx.y;
  const int b = bh >> 3, h = bh & 7;
  const int eb = blockIdx.x*128;

  {
    const uint4* Wg4 = (const uint4*)(W2p + (size_t)h*144*32);
    for (int fi = tid; fi < 1088; fi += 256)   // 136*32 dwords = 1088 uint4
      ((uint4*)Wl)[fi] = Wg4[fi];
  }
  for (int it = tid; it < 288; it += 256){
    int rix = it >> 5, p = it & 31;
    rCT[p*9 + rix] = ropeC[it];
    rST[p*9 + rix] = ropeS[it];
  }
  __syncthreads();

  const int og = tid & 7;            // d-octant: rope pairs [og*4, og*4+4)
  const int qd = tid >> 3;           // edge-quad in block (0..31)
  const int e0 = eb + qd*4;
  const int p0 = og*4;
  const float* ub = u + ((size_t)(b*512 + h*64))*2048;
  const float* h2b = h2t + (size_t)b*16*E;

  int iiv[4], jjv[4], rxv[4];
  #pragma unroll
  for (int s = 0; s < 4; s++){
    int ge = e0 + s;
    int gi = (ge < E) ? ge : (E-1);
    iiv[s] = ei[gi]; jjv[s] = ej[gi];
    rxv[s] = iiv[s] - jjv[s] + 4;
  }

  float dA[4][4], dB[4][4];
  #pragma unroll
  for (int s = 0; s < 4; s++){
    #pragma unroll
    for (int q = 0; q < 4; q++){
      int dp = p0 + q;
      float c  = rCT[dp*9 + rxv[s]];
      float sn = rST[dp*9 + rxv[s]];
      float ui0 = ub[(size_t)dp*2048 + iiv[s]];
      float ui1 = ub[(size_t)(dp+32)*2048 + iiv[s]];
      float uj0 = ub[(size_t)dp*2048 + jjv[s]];
      float uj1 = ub[(size_t)(dp+32)*2048 + jjv[s]];
      dA[s][q] = ui0*c - ui1*sn - uj0;
      dB[s][q] = ui1*c + ui0*sn - uj1;
    }
  }

  const uint4* Wl4 = (const uint4*)Wl;
  float P[4][8] = {};
  for (int k = 0; k < 17; k++){      // rolled; m from global (coalesced f4)
    float mk0, mk1, mk2, mk3;
    if (k < 16){
      float4 m4 = *(const float4*)(h2b + (size_t)k*E + e0);
      mk0 = m4.x; mk1 = m4.y; mk2 = m4.z; mk3 = m4.w;
    } else {
      mk0 = mk1 = mk2 = mk3 = 1.f;
    }
    const int rowb = (k*8)*8;        // uint4 index of row k*8
    #pragma unroll
    for (int r = 0; r < 8; r++){
      uint4 w = Wl4[rowb + r*8 + og];    // 4 (dp, dp+32) pairs
      float wa0 = blo(w.x), wb0 = bhi(w.x);
      float wa1 = blo(w.y), wb1 = bhi(w.y);
      float wa2 = blo(w.z), wb2 = bhi(w.z);
      float wa3 = blo(w.w), wb3 = bhi(w.w);
      #pragma unroll
      for (int s = 0; s < 4; s++){
        float pd;
        pd = dA[s][0]*wa0;
        pd = fmaf(dB[s][0], wb0, pd);
        pd = fmaf(dA[s][1], wa1, pd);
        pd = fmaf(dB[s][1], wb1, pd);
        pd = fmaf(dA[s][2], wa2, pd);
        pd = fmaf(dB[s][2], wb2, pd);
        pd = fmaf(dA[s][3], wa3, pd);
        pd = fmaf(dB[s][3], wb3, pd);
        float mk = (s==0)?mk0:(s==1)?mk1:(s==2)?mk2:mk3;
        P[s][r] = fmaf(mk, pd, P[s][r]);
      }
    }
  }

  // combine 8 d-octants within each edge-quad group
  #pragma unroll
  for (int s = 0; s < 4; s++)
    #pragma unroll
    for (int r = 0; r < 8; r++){
      float v = P[s][r];
      v += __shfl_xor(v, 1);
      v += __shfl_xor(v, 2);
      v += __shfl_xor(v, 4);
      P[s][r] = v;
    }

  // lanes og<4 own edge e0+og
  if (og < 4){
    int ge = e0 + og;
    if (ge < E){
      float S8[8];
      #pragma unroll
      for (int r = 0; r < 8; r++){
        float v0 = P[0][r], v1 = P[1][r], v2 = P[2][r], v3 = P[3][r];
        S8[r] = (og==0) ? v0 : (og==1) ? v1 : (og==2) ? v2 : v3;
      }
      const float* ig = ivsq + ((size_t)bh*E + ge)*8;
      float* cg = coefg + ((size_t)bh*E + ge)*8;
      #pragma unroll
      for (int r = 0; r < 8; r++) cg[r] = ig[r]*S8[r];
    }
  }
}

// ---------------------------------------------------------------------------
// k_apply v2c (validated round 11).
// ---------------------------------------------------------------------------
__global__ __launch_bounds__(256) void k_apply(
    const float* __restrict__ uin, float* __restrict__ uout,
    const float* __restrict__ W2,
    const float* __restrict__ h2e, const float* __restrict__ coefg,
    const float* __restrict__ alphas,
    const float* __restrict__ ropeC, const float* __restrict__ ropeS,
    const int* __restrict__ esrc, const int* __restrict__ edst,
    const int* __restrict__ ei, const int* __restrict__ ej,
    const float* __restrict__ eta, int E, int t)
{
  __shared__ float smem[10816];
  float* Al  = smem;                   // 9216 (union)
  float* UtF = smem;                   //   Ut 72*68 = 4896
  float* SaF = smem + 4896;            //   Sa 1024
  int*   Es  = (int*)(smem + 9216);    // 1024
  float* rCl = smem + 10240;           // 288
  float* rSl = smem + 10528;           // 288

  const int tid = threadIdx.x;
  const int l0 = blockIdx.x * 64;
  const int bh = blockIdx.y;
  const int b = bh >> 3, h = bh & 7;
  const float* ub = uin + ((size_t)(b*512 + h*64))*2048;
  float*       uo = uout + ((size_t)(b*512 + h*64))*2048;
  const float* Wg = W2 + (size_t)h*144*64;

  // ---- P0
  #pragma unroll
  for (int it = 0; it < 4; it++){
    int si = it*256 + tid;
    int o = si >> 6, ll = si & 63;
    Es[si] = (o < 8) ? esrc[o*L_ + l0 + ll] : edst[(o-8)*L_ + l0 + ll];
  }
  for (int it = tid; it < 288; it += 256){ rCl[it] = ropeC[it]; rSl[it] = ropeS[it]; }
  for (int it = tid; it < 9216; it += 256) Al[it] = 0.f;
  __syncthreads();

  // ---- P1: A-build. thread = (l, kc). kc owns k in [kc*4, kc*4+4) (+k16 for kc3).
  {
    const int l = tid & 63;
    const int kc = tid >> 6;
    const int kbase = kc*4;
    float areg[5][8];
    #pragma unroll
    for (int k = 0; k < 5; k++)
      #pragma unroll
      for (int r = 0; r < 8; r++) areg[k][r] = 0.f;
    for (int o = 0; o < 16; o++){
      int e = Es[o*64 + l];
      if (e < 0) continue;
      float sign = (o < 8) ? 1.f : -1.f;
      const float* hp = h2e + ((size_t)b*E + e)*16;
      const float* cp = coefg + ((size_t)bh*E + e)*8;
      float4 m4 = *(const float4*)(hp + kbase);
      float4 c0 = *(const float4*)cp;
      float4 c1 = *(const float4*)(cp + 4);
      float cf[8] = {c0.x, c0.y, c0.z, c0.w, c1.x, c1.y, c1.z, c1.w};
      float smv[4] = {sign*m4.x, sign*m4.y, sign*m4.z, sign*m4.w};
      #pragma unroll
      for (int k = 0; k < 4; k++)
        #pragma unroll
        for (int r = 0; r < 8; r++)
          areg[k][r] = fmaf(smv[k], cf[r], areg[k][r]);
      if (kc == 3){
        #pragma unroll
        for (int r = 0; r < 8; r++) areg[4][r] += sign*cf[r];
      }
    }
    // write swizzled: element n stored at f4-slot (n>>2)^sw (sw = (l>>2)&3)
    const int sw = (l >> 2) & 3;
    #pragma unroll
    for (int k = 0; k < 4; k++){
      #pragma unroll
      for (int r = 0; r < 8; r++){
        int n = (kbase + k)*8 + r;
        Al[l*144 + (((n >> 2) ^ sw) << 2) + (n & 3)] = areg[k][r];
      }
    }
    if (kc == 3){
      #pragma unroll
      for (int r = 0; r < 8; r++){
        int n = 128 + r;
        Al[l*144 + (((n >> 2) ^ sw) << 2) + (n & 3)] = areg[4][r];
      }
    }
  }
  __syncthreads();

  // ---- P2: GEMM acc[tt][q] = sum_{n<136} A[lg*4+tt][n] * W[n][dg*4+q]
  const int lg = tid & 15, dg = tid >> 4;
  float acc[4][4] = {};
  {
    const int swr = lg & 3;
    for (int nf4 = 0; nf4 < 34; nf4++){
      int sf4 = (nf4 ^ swr) << 2;
      float4 Av[4];
      #pragma unroll
      for (int tt = 0; tt < 4; tt++)
        Av[tt] = *(const float4*)&Al[(lg*4 + tt)*144 + sf4];
      int n = nf4*4;
      #pragma unroll
      for (int q = 0; q < 4; q++){
        float4 wb = *(const float4*)(Wg + (size_t)(n + q)*64 + dg*4);
        #pragma unroll
        for (int tt = 0; tt < 4; tt++){
          float a = (q==0)?Av[tt].x:(q==1)?Av[tt].y:(q==2)?Av[tt].z:Av[tt].w;
          acc[tt][0] = fmaf(a, wb.x, acc[tt][0]);
          acc[tt][1] = fmaf(a, wb.y, acc[tt][1]);
          acc[tt][2] = fmaf(a, wb.z, acc[tt][2]);
          acc[tt][3] = fmaf(a, wb.w, acc[tt][3]);
        }
      }
    }
  }
  __syncthreads();

  // ---- P3: load u tile [l0-4, l0+68) x 64d into Ut[l'][d] (stride 68); Sa.
  #pragma unroll
  for (int it = 0; it < 18; it++){
    int flat = it*256 + tid;          // 4608 = 64*72
    int d = flat / 72;
    int c = flat - d*72;
    int col = l0 - 4 + c;
    col = (col < 0) ? 0 : ((col > 2047) ? 2047 : col);
    UtF[c*68 + d] = ub[(size_t)d*2048 + col];
  }
  #pragma unroll
  for (int it = 0; it < 4; it++){
    int si = it*256 + tid;
    int e = Es[si];
    SaF[si] = (e >= 0) ? alphas[(size_t)b*E + e] : 0.f;
  }
  __syncthreads();

  // ---- P4: epilogue.
  const int pbase = (dg*4) & 31;
  const float sgn = (dg < 8) ? -1.f : 1.f;    // rot = c*u + sgn*s*u_pair
  const int pcol = (dg*4 + 32) & 63;
  float4 rcv[8], rsv[8];
  #pragma unroll
  for (int o = 0; o < 8; o++){
    const int rix = 4 - off_of(o);
    rcv[o] = *(const float4*)&rCl[rix*32 + pbase];
    rsv[o] = *(const float4*)&rSl[rix*32 + pbase];
  }
  #pragma unroll
  for (int tt = 0; tt < 4; tt++){
    const int ll = lg*4 + tt;
    const int myl = l0 + ll;
    const int lrel = ll + 4;
    const float et = eta[t*L_ + myl];
    float4 ul  = *(const float4*)&UtF[lrel*68 + dg*4];
    float4 ulp = *(const float4*)&UtF[lrel*68 + pcol];
    float upd[4] = {acc[tt][0], acc[tt][1], acc[tt][2], acc[tt][3]};
    float ulv[4] = {ul.x, ul.y, ul.z, ul.w};
    float ulpv[4] = {ulp.x, ulp.y, ulp.z, ulp.w};
    // src edges: myl = i; j = myl + off
    #pragma unroll
    for (int o = 0; o < 8; o++){
      int e = Es[o*64 + ll];
      if (e >= 0){
        float al = SaF[o*64 + ll];
        float4 uj = *(const float4*)&UtF[(lrel + off_of(o))*68 + dg*4];
        float ujv[4] = {uj.x, uj.y, uj.z, uj.w};
        float rc[4] = {rcv[o].x, rcv[o].y, rcv[o].z, rcv[o].w};
        float rs[4] = {rsv[o].x, rsv[o].y, rsv[o].z, rsv[o].w};
        #pragma unroll
        for (int q = 0; q < 4; q++){
          float rope = rc[q]*ulv[q] + sgn*rs[q]*ulpv[q];
          upd[q] = fmaf(al, rope - ujv[q], upd[q]);
        }
      }
    }
    // dst edges: myl = j; i = myl - off
    #pragma unroll
    for (int o = 0; o < 8; o++){
      int e = Es[(8 + o)*64 + ll];
      if (e >= 0){
        float al = SaF[(8 + o)*64 + ll];
        int lr2 = lrel - off_of(o);
        float4 ui  = *(const float4*)&UtF[lr2*68 + dg*4];
        float4 uip = *(const float4*)&UtF[lr2*68 + pcol];
        float uiv[4] = {ui.x, ui.y, ui.z, ui.w};
        float uipv[4] = {uip.x, uip.y, uip.z, uip.w};
        float rc[4] = {rcv[o].x, rcv[o].y, rcv[o].z, rcv[o].w};
        float rs[4] = {rsv[o].x, rsv[o].y, rsv[o].z, rsv[o].w};
        #pragma unroll
        for (int q = 0; q < 4; q++){
          float rope = rc[q]*uiv[q] + sgn*rs[q]*uipv[q];
          upd[q] -= al * (rope - ulv[q]);
        }
      }
    }
    #pragma unroll
    for (int q = 0; q < 4; q++)
      uo[(size_t)(dg*4 + q)*2048 + myl] = ulv[q] - et*upd[q];
  }
}

// ---------------------------------------------------------------------------
// k_out: out[b,l,n] = u[b,:,l] @ out_w[:,n] + out_b[n], f32 store.
// ---------------------------------------------------------------------------
__global__ __launch_bounds__(256) void k_out(
    const float* __restrict__ u, const float* __restrict__ w,
    const float* __restrict__ bias, float* __restrict__ outp)
{
  __shared__ float As[16][64];
  __shared__ float Bs[16][64];
  const int m0 = blockIdx.x * 64;
  const int n0 = blockIdx.y * 64;
  const int tid = threadIdx.x;
  const int ty = tid >> 4, tx = tid & 15;
  const int bb = m0 >> 11;
  const int l0 = m0 & 2047;
  float acc[4][4] = {};
  for (int k0 = 0; k0 < 512; k0 += 16){
    {
      int k = tid >> 4, ls = (tid & 15)*4;
      float4 v = *(const float4*)&u[((size_t)(bb*512 + k0 + k))*2048 + l0 + ls];
      *(float4*)&As[k][ls] = v;
    }
    {
      int k = tid >> 4, c = (tid & 15)*4;
      float4 v = *(const float4*)(w + (size_t)(k0 + k)*512 + n0 + c);
      *(float4*)&Bs[k][c] = v;
    }
    __syncthreads();
    #pragma unroll
    for (int k = 0; k < 16; k++){
      float4 a = *(const float4*)(&As[k][ty*4]);
      float4 b = *(const float4*)(&Bs[k][tx*4]);
      float av[4] = {a.x, a.y, a.z, a.w};
      float bv[4] = {b.x, b.y, b.z, b.w};
      #pragma unroll
      for (int ii = 0; ii < 4; ii++)
        #pragma unroll
        for (int jj = 0; jj < 4; jj++)
          acc[ii][jj] = fmaf(av[ii], bv[jj], acc[ii][jj]);
    }
    __syncthreads();
  }
  float bv[4];
  #pragma unroll
  for (int jj = 0; jj < 4; jj++) bv[jj] = bias[n0 + tx*4 + jj];
  #pragma unroll
  for (int ii = 0; ii < 4; ii++){
    int l = l0 + ty*4 + ii;
    float4 o;
    o.x = acc[ii][0] + bv[0];
    o.y = acc[ii][1] + bv[1];
    o.z = acc[ii][2] + bv[2];
    o.w = acc[ii][3] + bv[3];
    *(float4*)&outp[((size_t)(bb*2048 + l))*512 + n0 + tx*4] = o;
  }
}

// ---------------------------------------------------------------------------
extern "C" void kernel_launch(void* const* d_in, const int* in_sizes, int n_in,
                              void* d_out, int out_size, void* d_ws, size_t ws_size,
                              hipStream_t stream)
{
  const float* x    = (const float*)d_in[0];
  const int*   ei   = (const int*)d_in[1];
  const int*   ej   = (const int*)d_in[2];
  const float* tew  = (const float*)d_in[3];
  const float* teb  = (const float*)d_in[4];
  const float* a1w  = (const float*)d_in[5];
  const float* a1b  = (const float*)d_in[6];
  const float* a2w  = (const float*)d_in[7];
  const float* a2b  = (const float*)d_in[8];
  const float* l1w  = (const float*)d_in[9];
  const float* l1b  = (const float*)d_in[10];
  const float* l2w  = (const float*)d_in[11];
  const float* l2b  = (const float*)d_in[12];
  const float* step = (const float*)d_in[13];
  const float* ow   = (const float*)d_in[14];
  const float* ob   = (const float*)d_in[15];
  float* outp = (float*)d_out;
  const int E = in_sizes[1];

  char* p = (char*)d_ws;
  auto carve = [&](size_t nbytes)->char*{
    char* q = p; p += (nbytes + 255) & ~(size_t)255; return q;
  };
  float* u0     = (float*)carve((size_t)B_*512*2048*4);
  float* u1     = (float*)carve((size_t)B_*512*2048*4);
  float* PQ     = (float*)carve((size_t)B_*L_*64*4);
  float* h2e    = (float*)carve((size_t)B_*E*16*4);
  float* h2t    = (float*)carve((size_t)(B_*16*E + 64)*4);
  float* alphas = (float*)carve((size_t)B_*E*4);
  float* coefg  = (float*)carve((size_t)B_*NH_*E*8*4);
  float* ivsq   = (float*)carve((size_t)B_*NH_*E*8*4);
  float* W2     = (float*)carve((size_t)NH_*144*64*4);
  uint32* W2p   = (uint32*)carve((size_t)NH_*144*32*4);
  float* Gram   = (float*)carve((size_t)8*8*17*17*4);
  float* eta    = (float*)carve((size_t)T_*L_*4);
  float* ropeC  = (float*)carve((size_t)288*4);
  float* ropeS  = (float*)carve((size_t)288*4);
  int*   esrc   = (int*)carve((size_t)8*L_*4);
  int*   edst   = (int*)carve((size_t)8*L_*4);

  {
    int total = NH_*144*64 + T_*L_ + 9*32 + 2*8*L_;
    k_misc<<<dim3((total + 255)/256), dim3(256), 0, stream>>>(
        l2w, l2b, step, W2, eta, ropeC, ropeS, esrc, edst);
  }
  k_cvtw<<<dim3((NH_*144*32 + 255)/256), dim3(256), 0, stream>>>(W2, W2p);
  k_gram<<<dim3((8*8*17*17 + 255)/256), dim3(256), 0, stream>>>(W2, Gram);
  k_fill<<<dim3((E + 255)/256), dim3(256), 0, stream>>>(ei, ej, E, esrc, edst);
  k_te<<<dim3(64, 8), dim3(256), 0, stream>>>(x, tew, teb, u0);
  k_pq<<<dim3(64), dim3(256), 0, stream>>>(x, a1w, l1w, PQ);
  k_feat2<<<dim3((E + 255)/256, B_), dim3(256), 0, stream>>>(
      PQ, ei, ej, a1b, a2w, a2b, l1b, E, alphas, h2e, h2t);

  k_norm<<<dim3((E + 255)/256, B_*NH_), dim3(256), 0, stream>>>(Gram, h2e, E, ivsq);

  const int etiles = (E + 127)/128;
  float* ucur = u0;
  float* unxt = u1;
  for (int t = 0; t < T_; t++){
    k_S<<<dim3(etiles, B_*NH_), dim3(256), 0, stream>>>(
        ucur, W2p, h2t, ropeC, ropeS, ei, ej, E, ivsq, coefg);
    k_apply<<<dim3(L_/64, B_*NH_), dim3(256), 0, stream>>>(
        ucur, unxt, W2, h2e, coefg, alphas, ropeC, ropeS,
        esrc, edst, ei, ej, eta, E, t);
    float* tmp = ucur; ucur = unxt; unxt = tmp;
  }

  k_out<<<dim3(64, 8), dim3(256), 0, stream>>>(ucur, ow, ob, outp);
}

// Round 17
// 357.135 us; speedup vs baseline: 1.0655x; 1.0655x over previous
//
#include <hip/hip_runtime.h>
#include <hip/hip_bf16.h>

#define B_   2
#define L_   2048
#define DIM_ 512
#define NH_  8
#define HD_  64
#define R_   8
#define EH_  16
#define T_   2

__device__ __forceinline__ float gelu_f(float x){
  return 0.5f * x * (1.0f + erff(x * 0.70710678118654752f));
}
__device__ __forceinline__ float softplus_f(float x){
  return (x > 20.f) ? x : log1pf(expf(x));
}
__device__ __forceinline__ constexpr int off_of(int o){ return (o < 4) ? o - 4 : o - 3; }

// ---------------------------------------------------------------------------
// k_misc: W2[h][n=k*8+r][d] (k<16: l2w, k==16: bias, k==17: zero pad),
//         eta, rope tables, init edge slot tables to -1.
// ---------------------------------------------------------------------------
__global__ __launch_bounds__(256) void k_misc(
    const float* __restrict__ l2w, const float* __restrict__ l2b,
    const float* __restrict__ step,
    float* __restrict__ W2, float* __restrict__ eta,
    float* __restrict__ ropeC, float* __restrict__ ropeS,
    int* __restrict__ esrc, int* __restrict__ edst)
{
  int idx = blockIdx.x * 256 + threadIdx.x;
  if (idx < NH_*144*64){
    int d = idx & 63;
    int n = (idx >> 6) % 144;
    int h = idx / (144*64);
    int k = n >> 3, r = n & 7;
    int col = h*512 + r*64 + d;
    float v = 0.f;
    if (k < 16) v = l2w[k*4096 + col];
    else if (k == 16) v = l2b[col];
    W2[idx] = v;
    return;
  }
  idx -= NH_*144*64;
  if (idx < T_*L_){ eta[idx] = softplus_f(step[idx]); return; }
  idx -= T_*L_;
  if (idx < 9*32){
    int d = idx & 31, rel = (idx >> 5) - 4;
    float invf = expf(-((float)d / 32.f) * 9.210340371976184f);  // ln(10000)
    float ang = (float)rel * invf;
    ropeC[idx] = cosf(ang); ropeS[idx] = sinf(ang);
    return;
  }
  idx -= 9*32;
  if (idx < 2*8*L_){
    if (idx < 8*L_) esrc[idx] = -1; else edst[idx - 8*L_] = -1;
    return;
  }
}

// ---------------------------------------------------------------------------
// k_gram: Gram[h][r][a][b] = sum_d W2[h][a*8+r][d] * W2[h][b*8+r][d]
// ---------------------------------------------------------------------------
__global__ __launch_bounds__(256) void k_gram(
    const float* __restrict__ W2, float* __restrict__ Gram)
{
  int idx = blockIdx.x * 256 + threadIdx.x;
  if (idx >= 8*8*17*17) return;
  int bq = idx % 17;
  int a  = (idx / 17) % 17;
  int r  = (idx / 289) & 7;
  int h  = idx / (289*8);
  const float* wa = W2 + ((size_t)(h*144 + a*8 + r))*64;
  const float* wb = W2 + ((size_t)(h*144 + bq*8 + r))*64;
  float s = 0.f;
  #pragma unroll 8
  for (int d = 0; d < 64; d++) s = fmaf(wa[d], wb[d], s);
  Gram[idx] = s;
}

// ---------------------------------------------------------------------------
// k_fill: scatter edge ids into per-node slot tables.
// ---------------------------------------------------------------------------
__global__ __launch_bounds__(256) void k_fill(
    const int* __restrict__ ei, const int* __restrict__ ej, int E,
    int* __restrict__ esrc, int* __restrict__ edst)
{
  int e = blockIdx.x * 256 + threadIdx.x;
  if (e >= E) return;
  int i = ei[e], j = ej[e];
  int o = j - i;                      // in [-4,4] \ {0}
  int slot = (o < 0) ? (o + 4) : (o + 3);
  esrc[slot*L_ + i] = e;
  edst[slot*L_ + j] = e;
}

// ---------------------------------------------------------------------------
// k_te: u[(b*512 + n)*2048 + l] = x[b,l,:] @ te_w[:,n] + te_b[n]   (d-major u)
// ---------------------------------------------------------------------------
__global__ __launch_bounds__(256) void k_te(
    const float* __restrict__ x, const float* __restrict__ w,
    const float* __restrict__ bias, float* __restrict__ u)
{
  __shared__ float As[16][64];
  __shared__ float Bs[16][64];
  const int m0 = blockIdx.x * 64;
  const int n0 = blockIdx.y * 64;
  const int tid = threadIdx.x;
  const int ty = tid >> 4, tx = tid & 15;
  float acc[4][4] = {};
  for (int k0 = 0; k0 < 512; k0 += 16){
    {
      int m = tid >> 2, seg = tid & 3;
      float4 v = *(const float4*)(x + (size_t)(m0 + m)*512 + k0 + seg*4);
      As[seg*4+0][m] = v.x; As[seg*4+1][m] = v.y;
      As[seg*4+2][m] = v.z; As[seg*4+3][m] = v.w;
    }
    {
      int k = tid >> 4, c = (tid & 15)*4;
      float4 v = *(const float4*)(w + (size_t)(k0 + k)*512 + n0 + c);
      *(float4*)&Bs[k][c] = v;
    }
    __syncthreads();
    #pragma unroll
    for (int k = 0; k < 16; k++){
      float4 a = *(const float4*)(&As[k][ty*4]);
      float4 b = *(const float4*)(&Bs[k][tx*4]);
      float av[4] = {a.x, a.y, a.z, a.w};
      float bv[4] = {b.x, b.y, b.z, b.w};
      #pragma unroll
      for (int ii = 0; ii < 4; ii++)
        #pragma unroll
        for (int jj = 0; jj < 4; jj++)
          acc[ii][jj] = fmaf(av[ii], bv[jj], acc[ii][jj]);
    }
    __syncthreads();
  }
  const int bb = m0 >> 11;
  const int lb = (m0 & 2047) + ty*4;
  #pragma unroll
  for (int jj = 0; jj < 4; jj++){
    int n = n0 + tx*4 + jj;
    float bv = bias[n];
    float4 o;
    o.x = acc[0][jj] + bv; o.y = acc[1][jj] + bv;
    o.z = acc[2][jj] + bv; o.w = acc[3][jj] + bv;
    *(float4*)&u[((size_t)(bb*512 + n))*2048 + lb] = o;
  }
}

// ---------------------------------------------------------------------------
// k_pq: node projections for both edge MLPs.
// ---------------------------------------------------------------------------
__global__ __launch_bounds__(256) void k_pq(
    const float* __restrict__ x, const float* __restrict__ a1w,
    const float* __restrict__ l1w, float* __restrict__ PQ)
{
  __shared__ float As[16][64];
  __shared__ float Bs[16][64];
  const int m0 = blockIdx.x * 64;
  const int tid = threadIdx.x;
  const int ty = tid >> 4, tx = tid & 15;
  const int c = (tid & 15) * 4;
  const int group = c >> 4;                 // 0..3
  const float* src = (group & 2) ? l1w : a1w;
  const int krow_off = (group & 1) ? 512 : 0;
  const int cc = c & 15;
  float acc[4][4] = {};
  for (int k0 = 0; k0 < 512; k0 += 16){
    {
      int m = tid >> 2, seg = tid & 3;
      float4 v = *(const float4*)(x + (size_t)(m0 + m)*512 + k0 + seg*4);
      As[seg*4+0][m] = v.x; As[seg*4+1][m] = v.y;
      As[seg*4+2][m] = v.z; As[seg*4+3][m] = v.w;
    }
    {
      int k = tid >> 4;
      float4 v = *(const float4*)(src + (size_t)(krow_off + k0 + k)*16 + cc);
      *(float4*)&Bs[k][c] = v;
    }
    __syncthreads();
    #pragma unroll
    for (int k = 0; k < 16; k++){
      float4 a = *(const float4*)(&As[k][ty*4]);
      float4 b = *(const float4*)(&Bs[k][tx*4]);
      float av[4] = {a.x, a.y, a.z, a.w};
      float bv[4] = {b.x, b.y, b.z, b.w};
      #pragma unroll
      for (int ii = 0; ii < 4; ii++)
        #pragma unroll
        for (int jj = 0; jj < 4; jj++)
          acc[ii][jj] = fmaf(av[ii], bv[jj], acc[ii][jj]);
    }
    __syncthreads();
  }
  #pragma unroll
  for (int ii = 0; ii < 4; ii++){
    int m = m0 + ty*4 + ii;
    float4 o;
    o.x = acc[ii][0]; o.y = acc[ii][1]; o.z = acc[ii][2]; o.w = acc[ii][3];
    *(float4*)&PQ[(size_t)m*64 + tx*4] = o;
  }
}

// ---------------------------------------------------------------------------
// k_feat2: alphas + h2e (e-major) + h2t (k-major, for k_S global-m reads).
// ---------------------------------------------------------------------------
__global__ __launch_bounds__(256) void k_feat2(
    const float* __restrict__ PQ, const int* __restrict__ ei, const int* __restrict__ ej,
    const float* __restrict__ a1b, const float* __restrict__ a2w,
    const float* __restrict__ a2b, const float* __restrict__ l1b,
    int E, float* __restrict__ alphas, float* __restrict__ h2e,
    float* __restrict__ h2t)
{
  int e = blockIdx.x * 256 + threadIdx.x;
  int b = blockIdx.y;
  if (e >= E) return;
  int i = ei[e], j = ej[e];
  const float* Pi = PQ + ((size_t)b*L_ + i)*64;
  const float* Pj = PQ + ((size_t)b*L_ + j)*64;
  float ha[16], hl[16];
  #pragma unroll
  for (int q = 0; q < 4; q++){
    float4 p1 = *(const float4*)(Pi + q*4);
    float4 q1 = *(const float4*)(Pj + 16 + q*4);
    float4 p2 = *(const float4*)(Pi + 32 + q*4);
    float4 q2 = *(const float4*)(Pj + 48 + q*4);
    ha[q*4+0] = p1.x + q1.x; ha[q*4+1] = p1.y + q1.y;
    ha[q*4+2] = p1.z + q1.z; ha[q*4+3] = p1.w + q1.w;
    hl[q*4+0] = p2.x + q2.x; hl[q*4+1] = p2.y + q2.y;
    hl[q*4+2] = p2.z + q2.z; hl[q*4+3] = p2.w + q2.w;
  }
  float av = a2b[0];
  #pragma unroll
  for (int n = 0; n < 16; n++){
    float g = gelu_f(ha[n] + a1b[n]);
    av += g * a2w[n];
  }
  alphas[(size_t)b*E + e] = softplus_f(av);
  float* he = h2e + ((size_t)b*E + e)*16;
  #pragma unroll
  for (int n = 0; n < 16; n++){
    float g = gelu_f(hl[n] + l1b[n]);
    he[n] = g;
    h2t[((size_t)b*16 + n)*E + e] = g;
  }
}

// ---------------------------------------------------------------------------
// k_norm (once, u-independent): ivsq[bh][e][r] = 1/max(m17^T Gram_r m17, 1e-24)
// ---------------------------------------------------------------------------
__global__ __launch_bounds__(256) void k_norm(
    const float* __restrict__ Gram, const float* __restrict__ h2e,
    int E, float* __restrict__ ivsq)
{
  __shared__ float Gl[8*289];
  __shared__ float Hl[256*17];
  const int tid = threadIdx.x;
  const int bh = blockIdx.y;
  const int b = bh >> 3, h = bh & 7;
  const int eb = blockIdx.x*256;
  for (int it = tid; it < 2312; it += 256) Gl[it] = Gram[(size_t)h*2312 + it];
  {
    int ge = eb + tid;
    const float* hp = h2e + ((size_t)b*E + (ge < E ? ge : 0))*16;
    #pragma unroll
    for (int q = 0; q < 4; q++){
      float4 v = *(const float4*)(hp + q*4);
      Hl[tid*17+q*4+0]=v.x; Hl[tid*17+q*4+1]=v.y;
      Hl[tid*17+q*4+2]=v.z; Hl[tid*17+q*4+3]=v.w;
    }
    Hl[tid*17+16] = 1.f;
  }
  __syncthreads();
  int ge = eb + tid;
  if (ge >= E) return;
  float m17[17];
  #pragma unroll
  for (int k = 0; k < 17; k++) m17[k] = Hl[tid*17+k];
  float* ig = ivsq + ((size_t)bh*E + ge)*8;
  #pragma unroll
  for (int r = 0; r < 8; r++){
    float ss = 0.f;
    for (int a = 0; a < 17; a++){
      float ma = Hl[tid*17 + a];           // runtime idx -> LDS (no scratch)
      const float* Gr = Gl + r*289 + a*17;
      float inner = 0.f;
      #pragma unroll
      for (int bq = 0; bq < 17; bq++)
        inner = fmaf(m17[bq], Gr[bq], inner);
      ss = fmaf(ma, inner, ss);
    }
    ig[r] = 1.f / fmaxf(ss, 1e-24f);
  }
}

// ---------------------------------------------------------------------------
// k_S v4 (round-13 best: 85.8 µs/launch, VALUBusy 64%): quad = 4 edges x 4
// d-quarters, W f32 in LDS, m from global k-major h2t. Experiments v5
// (W global), v6 (bf16 W), v7 (8-way split) all regressed — this is the
// balance point of VALU (~55 µs) and LDS issue (~44 µs).
// ---------------------------------------------------------------------------
__global__ __launch_bounds__(256) void k_S(
    const float* __restrict__ u, const float* __restrict__ W2,
    const float* __restrict__ h2t,
    const float* __restrict__ ropeC, const float* __restrict__ ropeS,
    const int* __restrict__ ei, const int* __restrict__ ej,
    int E, const float* __restrict__ ivsq, float* __restrict__ coefg)
{
  __shared__ float Wl[136*64];         // 34.8 KB
  __shared__ float rCT[288], rST[288]; // [p][rix] stride 9
  const int tid = threadIdx.x;
  const int bh = blockIdx.y;
  const int b = bh >> 3, h = bh & 7;
  const int eb = blockIdx.x*256;

  {
    const float* Wg = W2 + (size_t)h*144*64;
    for (int fi = tid; fi < 136*16; fi += 256){
      int n = fi >> 4, kq = (fi & 15)*4;
      *(float4*)&Wl[n*64 + kq] = *(const float4*)(Wg + (size_t)n*64 + kq);
    }
  }
  for (int it = tid; it < 288; it += 256){
    int rix = it >> 5, p = it & 31;
    rCT[p*9 + rix] = ropeC[it];
    rST[p*9 + rix] = ropeS[it];
  }
  __syncthreads();

  const int dq = tid & 3;            // d-quarter
  const int qd = tid >> 2;           // edge-quad in block (0..63)
  const int e0 = eb + qd*4;
  const int p0 = 8*dq;
  const float* ub = u + ((size_t)(b*512 + h*64))*2048;
  const float* h2b = h2t + (size_t)b*16*E;

  int iiv[4], jjv[4], rxv[4];
  #pragma unroll
  for (int s = 0; s < 4; s++){
    int ge = e0 + s;
    int gi = (ge < E) ? ge : (E-1);
    iiv[s] = ei[gi]; jjv[s] = ej[gi];
    rxv[s] = iiv[s] - jjv[s] + 4;
  }

  float dA[4][8], dB[4][8];
  #pragma unroll
  for (int s = 0; s < 4; s++){
    #pragma unroll
    for (int q = 0; q < 8; q++){
      int dp = p0 + q;
      float c  = rCT[dp*9 + rxv[s]];
      float sn = rST[dp*9 + rxv[s]];
      float ui0 = ub[(size_t)dp*2048 + iiv[s]];
      float ui1 = ub[(size_t)(dp+32)*2048 + iiv[s]];
      float uj0 = ub[(size_t)dp*2048 + jjv[s]];
      float uj1 = ub[(size_t)(dp+32)*2048 + jjv[s]];
      dA[s][q] = ui0*c - ui1*sn - uj0;
      dB[s][q] = ui1*c + ui0*sn - uj1;
    }
  }

  float P[4][8] = {};
  for (int k = 0; k < 17; k++){      // rolled; m from global (coalesced f4)
    float mk0, mk1, mk2, mk3;
    if (k < 16){
      float4 m4 = *(const float4*)(h2b + (size_t)k*E + e0);
      mk0 = m4.x; mk1 = m4.y; mk2 = m4.z; mk3 = m4.w;
    } else {
      mk0 = mk1 = mk2 = mk3 = 1.f;
    }
    const float* wk = Wl + (k*8)*64 + p0;
    #pragma unroll
    for (int r = 0; r < 8; r++){
      const float* wr = wk + r*64;
      float4 a0 = *(const float4*)(wr);
      float4 a1 = *(const float4*)(wr + 4);
      float4 b0 = *(const float4*)(wr + 32);
      float4 b1 = *(const float4*)(wr + 36);
      #pragma unroll
      for (int s = 0; s < 4; s++){
        float pd;
        pd = dA[s][0]*a0.x;
        pd = fmaf(dA[s][1], a0.y, pd);
        pd = fmaf(dA[s][2], a0.z, pd);
        pd = fmaf(dA[s][3], a0.w, pd);
        pd = fmaf(dA[s][4], a1.x, pd);
        pd = fmaf(dA[s][5], a1.y, pd);
        pd = fmaf(dA[s][6], a1.z, pd);
        pd = fmaf(dA[s][7], a1.w, pd);
        pd = fmaf(dB[s][0], b0.x, pd);
        pd = fmaf(dB[s][1], b0.y, pd);
        pd = fmaf(dB[s][2], b0.z, pd);
        pd = fmaf(dB[s][3], b0.w, pd);
        pd = fmaf(dB[s][4], b1.x, pd);
        pd = fmaf(dB[s][5], b1.y, pd);
        pd = fmaf(dB[s][6], b1.z, pd);
        pd = fmaf(dB[s][7], b1.w, pd);
        float mk = (s==0)?mk0:(s==1)?mk1:(s==2)?mk2:mk3;
        P[s][r] = fmaf(mk, pd, P[s][r]);
      }
    }
  }

  // combine d-quarters within each quad
  #pragma unroll
  for (int s = 0; s < 4; s++)
    #pragma unroll
    for (int r = 0; r < 8; r++){
      float v = P[s][r];
      v += __shfl_xor(v, 1);
      v += __shfl_xor(v, 2);
      P[s][r] = v;
    }

  // lane dq owns edge e0+dq
  int ge = e0 + dq;
  if (ge < E){
    float S8[8];
    #pragma unroll
    for (int r = 0; r < 8; r++){
      float v0 = P[0][r], v1 = P[1][r], v2 = P[2][r], v3 = P[3][r];
      S8[r] = (dq==0) ? v0 : (dq==1) ? v1 : (dq==2) ? v2 : v3;
    }
    const float* ig = ivsq + ((size_t)bh*E + ge)*8;
    float* cg = coefg + ((size_t)bh*E + ge)*8;
    #pragma unroll
    for (int r = 0; r < 8; r++) cg[r] = ig[r]*S8[r];
  }
}

// ---------------------------------------------------------------------------
// k_apply v2c (validated round 11).
// ---------------------------------------------------------------------------
__global__ __launch_bounds__(256) void k_apply(
    const float* __restrict__ uin, float* __restrict__ uout,
    const float* __restrict__ W2,
    const float* __restrict__ h2e, const float* __restrict__ coefg,
    const float* __restrict__ alphas,
    const float* __restrict__ ropeC, const float* __restrict__ ropeS,
    const int* __restrict__ esrc, const int* __restrict__ edst,
    const int* __restrict__ ei, const int* __restrict__ ej,
    const float* __restrict__ eta, int E, int t)
{
  __shared__ float smem[10816];
  float* Al  = smem;                   // 9216 (union)
  float* UtF = smem;                   //   Ut 72*68 = 4896
  float* SaF = smem + 4896;            //   Sa 1024
  int*   Es  = (int*)(smem + 9216);    // 1024
  float* rCl = smem + 10240;           // 288
  float* rSl = smem + 10528;           // 288

  const int tid = threadIdx.x;
  const int l0 = blockIdx.x * 64;
  const int bh = blockIdx.y;
  const int b = bh >> 3, h = bh & 7;
  const float* ub = uin + ((size_t)(b*512 + h*64))*2048;
  float*       uo = uout + ((size_t)(b*512 + h*64))*2048;
  const float* Wg = W2 + (size_t)h*144*64;

  // ---- P0
  #pragma unroll
  for (int it = 0; it < 4; it++){
    int si = it*256 + tid;
    int o = si >> 6, ll = si & 63;
    Es[si] = (o < 8) ? esrc[o*L_ + l0 + ll] : edst[(o-8)*L_ + l0 + ll];
  }
  for (int it = tid; it < 288; it += 256){ rCl[it] = ropeC[it]; rSl[it] = ropeS[it]; }
  for (int it = tid; it < 9216; it += 256) Al[it] = 0.f;
  __syncthreads();

  // ---- P1: A-build. thread = (l, kc). kc owns k in [kc*4, kc*4+4) (+k16 for kc3).
  {
    const int l = tid & 63;
    const int kc = tid >> 6;
    const int kbase = kc*4;
    float areg[5][8];
    #pragma unroll
    for (int k = 0; k < 5; k++)
      #pragma unroll
      for (int r = 0; r < 8; r++) areg[k][r] = 0.f;
    for (int o = 0; o < 16; o++){
      int e = Es[o*64 + l];
      if (e < 0) continue;
      float sign = (o < 8) ? 1.f : -1.f;
      const float* hp = h2e + ((size_t)b*E + e)*16;
      const float* cp = coefg + ((size_t)bh*E + e)*8;
      float4 m4 = *(const float4*)(hp + kbase);
      float4 c0 = *(const float4*)cp;
      float4 c1 = *(const float4*)(cp + 4);
      float cf[8] = {c0.x, c0.y, c0.z, c0.w, c1.x, c1.y, c1.z, c1.w};
      float smv[4] = {sign*m4.x, sign*m4.y, sign*m4.z, sign*m4.w};
      #pragma unroll
      for (int k = 0; k < 4; k++)
        #pragma unroll
        for (int r = 0; r < 8; r++)
          areg[k][r] = fmaf(smv[k], cf[r], areg[k][r]);
      if (kc == 3){
        #pragma unroll
        for (int r = 0; r < 8; r++) areg[4][r] += sign*cf[r];
      }
    }
    // write swizzled: element n stored at f4-slot (n>>2)^sw (sw = (l>>2)&3)
    const int sw = (l >> 2) & 3;
    #pragma unroll
    for (int k = 0; k < 4; k++){
      #pragma unroll
      for (int r = 0; r < 8; r++){
        int n = (kbase + k)*8 + r;
        Al[l*144 + (((n >> 2) ^ sw) << 2) + (n & 3)] = areg[k][r];
      }
    }
    if (kc == 3){
      #pragma unroll
      for (int r = 0; r < 8; r++){
        int n = 128 + r;
        Al[l*144 + (((n >> 2) ^ sw) << 2) + (n & 3)] = areg[4][r];
      }
    }
  }
  __syncthreads();

  // ---- P2: GEMM acc[tt][q] = sum_{n<136} A[lg*4+tt][n] * W[n][dg*4+q]
  const int lg = tid & 15, dg = tid >> 4;
  float acc[4][4] = {};
  {
    const int swr = lg & 3;
    for (int nf4 = 0; nf4 < 34; nf4++){
      int sf4 = (nf4 ^ swr) << 2;
      float4 Av[4];
      #pragma unroll
      for (int tt = 0; tt < 4; tt++)
        Av[tt] = *(const float4*)&Al[(lg*4 + tt)*144 + sf4];
      int n = nf4*4;
      #pragma unroll
      for (int q = 0; q < 4; q++){
        float4 wb = *(const float4*)(Wg + (size_t)(n + q)*64 + dg*4);
        #pragma unroll
        for (int tt = 0; tt < 4; tt++){
          float a = (q==0)?Av[tt].x:(q==1)?Av[tt].y:(q==2)?Av[tt].z:Av[tt].w;
          acc[tt][0] = fmaf(a, wb.x, acc[tt][0]);
          acc[tt][1] = fmaf(a, wb.y, acc[tt][1]);
          acc[tt][2] = fmaf(a, wb.z, acc[tt][2]);
          acc[tt][3] = fmaf(a, wb.w, acc[tt][3]);
        }
      }
    }
  }
  __syncthreads();

  // ---- P3: load u tile [l0-4, l0+68) x 64d into Ut[l'][d] (stride 68); Sa.
  #pragma unroll
  for (int it = 0; it < 18; it++){
    int flat = it*256 + tid;          // 4608 = 64*72
    int d = flat / 72;
    int c = flat - d*72;
    int col = l0 - 4 + c;
    col = (col < 0) ? 0 : ((col > 2047) ? 2047 : col);
    UtF[c*68 + d] = ub[(size_t)d*2048 + col];
  }
  #pragma unroll
  for (int it = 0; it < 4; it++){
    int si = it*256 + tid;
    int e = Es[si];
    SaF[si] = (e >= 0) ? alphas[(size_t)b*E + e] : 0.f;
  }
  __syncthreads();

  // ---- P4: epilogue.
  const int pbase = (dg*4) & 31;
  const float sgn = (dg < 8) ? -1.f : 1.f;    // rot = c*u + sgn*s*u_pair
  const int pcol = (dg*4 + 32) & 63;
  float4 rcv[8], rsv[8];
  #pragma unroll
  for (int o = 0; o < 8; o++){
    const int rix = 4 - off_of(o);
    rcv[o] = *(const float4*)&rCl[rix*32 + pbase];
    rsv[o] = *(const float4*)&rSl[rix*32 + pbase];
  }
  #pragma unroll
  for (int tt = 0; tt < 4; tt++){
    const int ll = lg*4 + tt;
    const int myl = l0 + ll;
    const int lrel = ll + 4;
    const float et = eta[t*L_ + myl];
    float4 ul  = *(const float4*)&UtF[lrel*68 + dg*4];
    float4 ulp = *(const float4*)&UtF[lrel*68 + pcol];
    float upd[4] = {acc[tt][0], acc[tt][1], acc[tt][2], acc[tt][3]};
    float ulv[4] = {ul.x, ul.y, ul.z, ul.w};
    float ulpv[4] = {ulp.x, ulp.y, ulp.z, ulp.w};
    // src edges: myl = i; j = myl + off
    #pragma unroll
    for (int o = 0; o < 8; o++){
      int e = Es[o*64 + ll];
      if (e >= 0){
        float al = SaF[o*64 + ll];
        float4 uj = *(const float4*)&UtF[(lrel + off_of(o))*68 + dg*4];
        float ujv[4] = {uj.x, uj.y, uj.z, uj.w};
        float rc[4] = {rcv[o].x, rcv[o].y, rcv[o].z, rcv[o].w};
        float rs[4] = {rsv[o].x, rsv[o].y, rsv[o].z, rsv[o].w};
        #pragma unroll
        for (int q = 0; q < 4; q++){
          float rope = rc[q]*ulv[q] + sgn*rs[q]*ulpv[q];
          upd[q] = fmaf(al, rope - ujv[q], upd[q]);
        }
      }
    }
    // dst edges: myl = j; i = myl - off
    #pragma unroll
    for (int o = 0; o < 8; o++){
      int e = Es[(8 + o)*64 + ll];
      if (e >= 0){
        float al = SaF[(8 + o)*64 + ll];
        int lr2 = lrel - off_of(o);
        float4 ui  = *(const float4*)&UtF[lr2*68 + dg*4];
        float4 uip = *(const float4*)&UtF[lr2*68 + pcol];
        float uiv[4] = {ui.x, ui.y, ui.z, ui.w};
        float uipv[4] = {uip.x, uip.y, uip.z, uip.w};
        float rc[4] = {rcv[o].x, rcv[o].y, rcv[o].z, rcv[o].w};
        float rs[4] = {rsv[o].x, rsv[o].y, rsv[o].z, rsv[o].w};
        #pragma unroll
        for (int q = 0; q < 4; q++){
          float rope = rc[q]*uiv[q] + sgn*rs[q]*uipv[q];
          upd[q] -= al * (rope - ulv[q]);
        }
      }
    }
    #pragma unroll
    for (int q = 0; q < 4; q++)
      uo[(size_t)(dg*4 + q)*2048 + myl] = ulv[q] - et*upd[q];
  }
}

// ---------------------------------------------------------------------------
// k_out: out[b,l,n] = u[b,:,l] @ out_w[:,n] + out_b[n], f32 store.
// ---------------------------------------------------------------------------
__global__ __launch_bounds__(256) void k_out(
    const float* __restrict__ u, const float* __restrict__ w,
    const float* __restrict__ bias, float* __restrict__ outp)
{
  __shared__ float As[16][64];
  __shared__ float Bs[16][64];
  const int m0 = blockIdx.x * 64;
  const int n0 = blockIdx.y * 64;
  const int tid = threadIdx.x;
  const int ty = tid >> 4, tx = tid & 15;
  const int bb = m0 >> 11;
  const int l0 = m0 & 2047;
  float acc[4][4] = {};
  for (int k0 = 0; k0 < 512; k0 += 16){
    {
      int k = tid >> 4, ls = (tid & 15)*4;
      float4 v = *(const float4*)&u[((size_t)(bb*512 + k0 + k))*2048 + l0 + ls];
      *(float4*)&As[k][ls] = v;
    }
    {
      int k = tid >> 4, c = (tid & 15)*4;
      float4 v = *(const float4*)(w + (size_t)(k0 + k)*512 + n0 + c);
      *(float4*)&Bs[k][c] = v;
    }
    __syncthreads();
    #pragma unroll
    for (int k = 0; k < 16; k++){
      float4 a = *(const float4*)(&As[k][ty*4]);
      float4 b = *(const float4*)(&Bs[k][tx*4]);
      float av[4] = {a.x, a.y, a.z, a.w};
      float bv[4] = {b.x, b.y, b.z, b.w};
      #pragma unroll
      for (int ii = 0; ii < 4; ii++)
        #pragma unroll
        for (int jj = 0; jj < 4; jj++)
          acc[ii][jj] = fmaf(av[ii], bv[jj], acc[ii][jj]);
    }
    __syncthreads();
  }
  float bv[4];
  #pragma unroll
  for (int jj = 0; jj < 4; jj++) bv[jj] = bias[n0 + tx*4 + jj];
  #pragma unroll
  for (int ii = 0; ii < 4; ii++){
    int l = l0 + ty*4 + ii;
    float4 o;
    o.x = acc[ii][0] + bv[0];
    o.y = acc[ii][1] + bv[1];
    o.z = acc[ii][2] + bv[2];
    o.w = acc[ii][3] + bv[3];
    *(float4*)&outp[((size_t)(bb*2048 + l))*512 + n0 + tx*4] = o;
  }
}

// ---------------------------------------------------------------------------
extern "C" void kernel_launch(void* const* d_in, const int* in_sizes, int n_in,
                              void* d_out, int out_size, void* d_ws, size_t ws_size,
                              hipStream_t stream)
{
  const float* x    = (const float*)d_in[0];
  const int*   ei   = (const int*)d_in[1];
  const int*   ej   = (const int*)d_in[2];
  const float* tew  = (const float*)d_in[3];
  const float* teb  = (const float*)d_in[4];
  const float* a1w  = (const float*)d_in[5];
  const float* a1b  = (const float*)d_in[6];
  const float* a2w  = (const float*)d_in[7];
  const float* a2b  = (const float*)d_in[8];
  const float* l1w  = (const float*)d_in[9];
  const float* l1b  = (const float*)d_in[10];
  const float* l2w  = (const float*)d_in[11];
  const float* l2b  = (const float*)d_in[12];
  const float* step = (const float*)d_in[13];
  const float* ow   = (const float*)d_in[14];
  const float* ob   = (const float*)d_in[15];
  float* outp = (float*)d_out;
  const int E = in_sizes[1];

  char* p = (char*)d_ws;
  auto carve = [&](size_t nbytes)->char*{
    char* q = p; p += (nbytes + 255) & ~(size_t)255; return q;
  };
  float* u0     = (float*)carve((size_t)B_*512*2048*4);
  float* u1     = (float*)carve((size_t)B_*512*2048*4);
  float* PQ     = (float*)carve((size_t)B_*L_*64*4);
  float* h2e    = (float*)carve((size_t)B_*E*16*4);
  float* h2t    = (float*)carve((size_t)(B_*16*E + 64)*4);
  float* alphas = (float*)carve((size_t)B_*E*4);
  float* coefg  = (float*)carve((size_t)B_*NH_*E*8*4);
  float* ivsq   = (float*)carve((size_t)B_*NH_*E*8*4);
  float* W2     = (float*)carve((size_t)NH_*144*64*4);
  float* Gram   = (float*)carve((size_t)8*8*17*17*4);
  float* eta    = (float*)carve((size_t)T_*L_*4);
  float* ropeC  = (float*)carve((size_t)288*4);
  float* ropeS  = (float*)carve((size_t)288*4);
  int*   esrc   = (int*)carve((size_t)8*L_*4);
  int*   edst   = (int*)carve((size_t)8*L_*4);

  {
    int total = NH_*144*64 + T_*L_ + 9*32 + 2*8*L_;
    k_misc<<<dim3((total + 255)/256), dim3(256), 0, stream>>>(
        l2w, l2b, step, W2, eta, ropeC, ropeS, esrc, edst);
  }
  k_gram<<<dim3((8*8*17*17 + 255)/256), dim3(256), 0, stream>>>(W2, Gram);
  k_fill<<<dim3((E + 255)/256), dim3(256), 0, stream>>>(ei, ej, E, esrc, edst);
  k_te<<<dim3(64, 8), dim3(256), 0, stream>>>(x, tew, teb, u0);
  k_pq<<<dim3(64), dim3(256), 0, stream>>>(x, a1w, l1w, PQ);
  k_feat2<<<dim3((E + 255)/256, B_), dim3(256), 0, stream>>>(
      PQ, ei, ej, a1b, a2w, a2b, l1b, E, alphas, h2e, h2t);

  k_norm<<<dim3((E + 255)/256, B_*NH_), dim3(256), 0, stream>>>(Gram, h2e, E, ivsq);

  const int etiles = (E + 255)/256;
  float* ucur = u0;
  float* unxt = u1;
  for (int t = 0; t < T_; t++){
    k_S<<<dim3(etiles, B_*NH_), dim3(256), 0, stream>>>(
        ucur, W2, h2t, ropeC, ropeS, ei, ej, E, ivsq, coefg);
    k_apply<<<dim3(L_/64, B_*NH_), dim3(256), 0, stream>>>(
        ucur, unxt, W2, h2e, coefg, alphas, ropeC, ropeS,
        esrc, edst, ei, ej, eta, E, t);
    float* tmp = ucur; ucur = unxt; unxt = tmp;
  }

  k_out<<<dim3(64, 8), dim3(256), 0, stream>>>(ucur, ow, ob, outp);
}